// Round 9
// baseline (36.034 us; speedup 1.0000x reference)
//
#include <hip/hip_runtime.h>

#define S 32768
#define NBLK 256
// float offsets into ws
#define WS_C4   0
#define WS_KQ   64
#define WS_MP   1088
#define WS_LP   2112
#define WS_YV   3136
#define WS_B2   4160
#define WS_M2   4416
#define WS_YP   266560
#define WS_CNT  528704  // 4 ints (cntA, cntM2, cntB, cntC)

__device__ __forceinline__ float dot4(float4 a, float4 b) {
  return a.x * b.x + a.y * b.y + a.z * b.z + a.w * b.w;
}

// ---- sync primitives (device-scope; co-residency guaranteed by coop launch) ----
__device__ __forceinline__ void signal_done(int* p) {
  __threadfence();
  __syncthreads();
  if (threadIdx.x == 0) atomicAdd(p, 1);
}
__device__ __forceinline__ void spin_until(int* p, int target) {
  if (threadIdx.x == 0) {
    while (atomicAdd(p, 0) < target) __builtin_amdgcn_s_sleep(2);
  }
  __syncthreads();
  __threadfence();
}
__device__ __forceinline__ int take_ticket(int* p, int* shi) {
  __threadfence();
  __syncthreads();
  if (threadIdx.x == 0) *shi = atomicAdd(p, 1);
  __syncthreads();
  return *shi;
}

// ---------------- Phase A parts ----------------
__device__ __forceinline__ void phaseA_kq(const float* __restrict__ x, const float* __restrict__ W,
                                          const float* __restrict__ inb, float* __restrict__ kq,
                                          float* __restrict__ c4, float* sh, int bid, int t) {
  float* xs = sh;          // 256
  float* qls = sh + 256;   // 64
  float* red = sh + 320;   // 512
  const int lane = t & 63, w = t >> 6;
  const int h = bid >> 2, qt = bid & 3;
  if (t < 256) xs[t] = x[t];
  __syncthreads();
  const float4 xv = *(const float4*)&xs[lane * 4];
#pragma unroll
  for (int k = 0; k < 8; ++k) {
    const int eloc = w * 8 + k;
    const int row = h * 64 + eloc;
    float4 wv = *(const float4*)&W[(size_t)row * 256 + lane * 4];
    float p = dot4(wv, xv);
#pragma unroll
    for (int m = 1; m < 64; m <<= 1) p += __shfl_xor(p, m);
    if (lane == 0) qls[eloc] = p + inb[row];
  }
  __syncthreads();
  const int cl = t & 63, ds = t >> 6;
  float acc = 0.f;
#pragma unroll
  for (int d2 = 0; d2 < 8; ++d2) {
    const int d = ds * 8 + d2;
    acc += W[(size_t)(256 + h * 64 + d) * 256 + qt * 64 + cl] * qls[d];
  }
  red[ds * 64 + cl] = acc;
  __syncthreads();
  if (ds == 0) {
    float s = 0.f;
#pragma unroll
    for (int i = 0; i < 8; ++i) s += red[i * 64 + cl];
    kq[h * 256 + qt * 64 + cl] = s;
  }
  if (qt == 0 && t < 64) {
    float v = qls[t] * inb[256 + h * 64 + t];
#pragma unroll
    for (int m = 1; m < 64; m <<= 1) v += __shfl_xor(v, m);
    if (t == 0) c4[h] = v;
  }
}

__device__ __forceinline__ void phaseA_m2(const float* __restrict__ W, const float* __restrict__ Wout,
                                          float* __restrict__ M2, float* sh, int b2, int t) {
  float* wout_t = sh;  // [8][64]
  const int tile = b2 >> 1, sub = b2 & 1;
  const int h = tile >> 4, e0 = (tile & 15) * 16 + sub * 8;
  {
    const int e = t >> 6, d = t & 63;
    wout_t[e * 64 + d] = Wout[(size_t)(e0 + e) * 256 + h * 64 + d];
  }
  __syncthreads();
  const int c = t & 255, eh = t >> 8;
  float acc[4] = {0.f, 0.f, 0.f, 0.f};
#pragma unroll 8
  for (int d = 0; d < 64; ++d) {
    const float wv = W[(size_t)(512 + h * 64 + d) * 256 + c];
#pragma unroll
    for (int e = 0; e < 4; ++e) acc[e] += wv * wout_t[(eh * 4 + e) * 64 + d];
  }
#pragma unroll
  for (int e = 0; e < 4; ++e)
    M2[(size_t)(e0 + eh * 4 + e) * 1024 + h * 256 + c] = acc[e];
}

// bias2[e] = Wout[e].bv + bout[e]; 16 blocks x 16 outputs
__device__ __forceinline__ void phaseA_b2(const float* __restrict__ Wout, const float* __restrict__ inb,
                                          const float* __restrict__ bout, float* __restrict__ bias2,
                                          float* sh, int b, int t) {
  float* red = sh;  // 512
  const int og = t >> 5, seg = t & 31;
  const int e = b * 16 + og;
  float acc = 0.f;
#pragma unroll
  for (int j = 0; j < 8; ++j)
    acc += Wout[(size_t)e * 256 + seg * 8 + j] * inb[512 + seg * 8 + j];
  red[og * 32 + seg] = acc;
  __syncthreads();
  if (t < 16) {
    float s = bout[b * 16 + t];
#pragma unroll
    for (int i = 0; i < 32; ++i) s += red[t * 32 + i];
    bias2[b * 16 + t] = s;
  }
}

// ---------------- Phase B ----------------
__device__ __forceinline__ float bscore(float4 xv, float4 kq0, float4 kq1, float4 kq2,
                                        float4 kq3, float c4v, int lane) {
  float p0 = dot4(xv, kq0), p1 = dot4(xv, kq1), p2 = dot4(xv, kq2), p3 = dot4(xv, kq3);
  const bool b1 = (lane & 2) != 0;
  float keep0 = b1 ? p2 : p0, send0 = b1 ? p0 : p2;
  keep0 += __shfl_xor(send0, 2);
  float keep1 = b1 ? p3 : p1, send1 = b1 ? p1 : p3;
  keep1 += __shfl_xor(send1, 2);
  const bool b0 = (lane & 1) != 0;
  float vv = b0 ? keep1 : keep0, sv = b0 ? keep0 : keep1;
  vv += __shfl_xor(sv, 1);
  vv += __shfl_xor(vv, 4);
  vv += __shfl_xor(vv, 8);
  vv += __shfl_xor(vv, 16);
  vv += __shfl_xor(vv, 32);
  return (vv + c4v) * 0.125f;
}

__device__ __forceinline__ void phaseB_core(const float4* xvA, const float4* xvB,
                                            const float* __restrict__ kq, const float* __restrict__ c4,
                                            float* __restrict__ ypart, float* __restrict__ mpart,
                                            float* __restrict__ lpart, float* sh, int bid, int t) {
  float* yls = sh;          // 8192
  float* sml = sh + 8192;   // 32
  float* sll = sh + 8224;   // 32
  const int lane = t & 63, w = t >> 6;
  const int hme = lane & 3;
  const float4 kq0 = *(const float4*)&kq[0 * 256 + lane * 4];
  const float4 kq1 = *(const float4*)&kq[1 * 256 + lane * 4];
  const float4 kq2 = *(const float4*)&kq[2 * 256 + lane * 4];
  const float4 kq3 = *(const float4*)&kq[3 * 256 + lane * 4];
  const float c4v = c4[hme];

  float vA[8];
#pragma unroll
  for (int r = 0; r < 8; ++r) vA[r] = bscore(xvA[r], kq0, kq1, kq2, kq3, c4v, lane);
  float m = vA[0];
#pragma unroll
  for (int r = 1; r < 8; ++r) m = fmaxf(m, vA[r]);

  float l = 0.f;
  float4 a[4];
#pragma unroll
  for (int k = 0; k < 4; ++k) a[k] = (float4){0.f, 0.f, 0.f, 0.f};
#pragma unroll
  for (int r = 0; r < 8; ++r) {
    const float e0 = __expf(vA[r] - m);
    l += e0;
    const float e1 = __shfl_xor(e0, 1);
    const float e2 = __shfl_xor(e0, 2);
    const float e3 = __shfl_xor(e0, 3);
    a[0].x += e0 * xvA[r].x; a[0].y += e0 * xvA[r].y; a[0].z += e0 * xvA[r].z; a[0].w += e0 * xvA[r].w;
    a[1].x += e1 * xvA[r].x; a[1].y += e1 * xvA[r].y; a[1].z += e1 * xvA[r].z; a[1].w += e1 * xvA[r].w;
    a[2].x += e2 * xvA[r].x; a[2].y += e2 * xvA[r].y; a[2].z += e2 * xvA[r].z; a[2].w += e2 * xvA[r].w;
    a[3].x += e3 * xvA[r].x; a[3].y += e3 * xvA[r].y; a[3].z += e3 * xvA[r].z; a[3].w += e3 * xvA[r].w;
  }

  float vB[8];
#pragma unroll
  for (int r = 0; r < 8; ++r) vB[r] = bscore(xvB[r], kq0, kq1, kq2, kq3, c4v, lane);
  float mB = vB[0];
#pragma unroll
  for (int r = 1; r < 8; ++r) mB = fmaxf(mB, vB[r]);

  // online merge with per-head rescale factors (verified R8)
  {
    const float mN = fmaxf(m, mB);
    const float fown = __expf(m - mN);
    l *= fown;
    const float f1 = __shfl_xor(fown, 1);
    const float f2 = __shfl_xor(fown, 2);
    const float f3 = __shfl_xor(fown, 3);
    a[0].x *= fown; a[0].y *= fown; a[0].z *= fown; a[0].w *= fown;
    a[1].x *= f1;   a[1].y *= f1;   a[1].z *= f1;   a[1].w *= f1;
    a[2].x *= f2;   a[2].y *= f2;   a[2].z *= f2;   a[2].w *= f2;
    a[3].x *= f3;   a[3].y *= f3;   a[3].z *= f3;   a[3].w *= f3;
    m = mN;
  }
#pragma unroll
  for (int r = 0; r < 8; ++r) {
    const float e0 = __expf(vB[r] - m);
    l += e0;
    const float e1 = __shfl_xor(e0, 1);
    const float e2 = __shfl_xor(e0, 2);
    const float e3 = __shfl_xor(e0, 3);
    a[0].x += e0 * xvB[r].x; a[0].y += e0 * xvB[r].y; a[0].z += e0 * xvB[r].z; a[0].w += e0 * xvB[r].w;
    a[1].x += e1 * xvB[r].x; a[1].y += e1 * xvB[r].y; a[1].z += e1 * xvB[r].z; a[1].w += e1 * xvB[r].w;
    a[2].x += e2 * xvB[r].x; a[2].y += e2 * xvB[r].y; a[2].z += e2 * xvB[r].z; a[2].w += e2 * xvB[r].w;
    a[3].x += e3 * xvB[r].x; a[3].y += e3 * xvB[r].y; a[3].z += e3 * xvB[r].z; a[3].w += e3 * xvB[r].w;
  }

  __syncthreads();
  if (lane < 4) { sml[w * 4 + lane] = m; sll[w * 4 + lane] = l; }
  __syncthreads();

#pragma unroll
  for (int k = 0; k < 4; ++k) {
    const int h = hme ^ k;
    float mb = sml[h];
#pragma unroll
    for (int i = 1; i < 8; ++i) mb = fmaxf(mb, sml[i * 4 + h]);
    const float f = __expf(sml[w * 4 + h] - mb);
    float4 av;
    av.x = a[k].x * f; av.y = a[k].y * f; av.z = a[k].z * f; av.w = a[k].w * f;
    *(float4*)&yls[w * 1024 + h * 256 + lane * 4] = av;
  }
  __syncthreads();

  if (t < 4) {
    float mb = sml[t];
#pragma unroll
    for (int i = 1; i < 8; ++i) mb = fmaxf(mb, sml[i * 4 + t]);
    float lb = 0.f;
#pragma unroll
    for (int i = 0; i < 8; ++i) lb += sll[i * 4 + t] * __expf(sml[i * 4 + t] - mb);
    mpart[t * NBLK + bid] = mb;
    lpart[t * NBLK + bid] = lb;
  }
  float* yp = &ypart[(size_t)bid * 1024];
#pragma unroll
  for (int o = t; o < 1024; o += 512) {
    float s = 0.f;
#pragma unroll
    for (int i = 0; i < 8; ++i) s += yls[i * 1024 + o];
    yp[o] = s;
  }
}

// ---------------- Phase C ----------------
__device__ __forceinline__ void phaseC(const float* __restrict__ ypart, const float* __restrict__ mpart,
                                       const float* __restrict__ lpart, float* __restrict__ yv,
                                       float* sh, int bid, int t) {
  float* mred = sh;           // 256
  float* scales = sh + 256;   // 256
  float* lred = sh + 512;     // 256
  float* sred = sh + 768;     // 512
  const int h = bid >> 4;
  const int o0 = bid * 16;
  if (t < 256) mred[t] = mpart[h * 256 + t];
  __syncthreads();
  for (int s = 128; s > 0; s >>= 1) {
    if (t < s) mred[t] = fmaxf(mred[t], mred[t + s]);
    __syncthreads();
  }
  const float mg = mred[0];
  if (t < 256) {
    const float sc = __expf(mpart[h * 256 + t] - mg);
    scales[t] = sc;
    lred[t] = lpart[h * 256 + t] * sc;
  }
  __syncthreads();
  for (int s = 128; s > 0; s >>= 1) {
    if (t < s) lred[t] += lred[t + s];
    __syncthreads();
  }
  const float inv = 1.0f / lred[0];
  const int ol = t & 15, bg = t >> 4;
  float s = 0.f;
#pragma unroll
  for (int j = 0; j < 8; ++j) {
    const int b = bg * 8 + j;
    s += ypart[(size_t)b * 1024 + o0 + ol] * scales[b];
  }
  sred[bg * 16 + ol] = s;
  __syncthreads();
  if (t < 16) {
    float tot = 0.f;
#pragma unroll
    for (int g = 0; g < 32; ++g) tot += sred[g * 16 + t];
    yv[o0 + t] = tot * inv;
  }
}

// ---------------- Phase D ----------------
__device__ __forceinline__ void phaseD(const float* __restrict__ M2, const float* __restrict__ yv,
                                       const float* __restrict__ bias2, float* __restrict__ out,
                                       float* sh, int bid, int t) {
  float* yls = sh;          // 1024
  float* smo = sh + 1024;   // 512
  for (int i = t; i < 1024; i += 512) yls[i] = yv[i];
  __syncthreads();
  const int og = t >> 5, seg = t & 31;
  const int e = bid * 16 + og;
  float acc = 0.f;
  const float4* m4 = (const float4*)&M2[(size_t)e * 1024 + seg * 32];
  const float4* y4 = (const float4*)&yls[seg * 32];
#pragma unroll
  for (int j = 0; j < 8; ++j) acc += dot4(m4[j], y4[j]);
  smo[og * 32 + seg] = acc;
  __syncthreads();
  if (t < 16) {
    float s = bias2[bid * 16 + t];
#pragma unroll
    for (int i = 0; i < 32; ++i) s += smo[t * 32 + i];
    out[bid * 16 + t] = s;
  }
}

// ---------------- Cooperative all-in-one, zero grid.sync ----------------
__global__ void __launch_bounds__(512, 1) mha_coop(const float* __restrict__ x,
                                                   const float* __restrict__ W,
                                                   const float* __restrict__ inb,
                                                   const float* __restrict__ Wout,
                                                   const float* __restrict__ bout,
                                                   float* __restrict__ out,
                                                   float* __restrict__ ws) {
  __shared__ __align__(16) float sh[8448];
  __shared__ int shi;
  const int t = threadIdx.x, bid = blockIdx.x;
  const int lane = t & 63, w = t >> 6;
  int* cnt = (int*)(ws + WS_CNT);
  float* c4 = ws + WS_C4;
  float* kq = ws + WS_KQ;
  float* mpart = ws + WS_MP;
  float* lpart = ws + WS_LP;
  float* yv = ws + WS_YV;
  float* bias2 = ws + WS_B2;
  float* M2 = ws + WS_M2;
  float* ypart = ws + WS_YP;

  const int r0 = bid * 128 + w * 16;
  float4 xvA[8], xvB[8];

  if (bid >= 16) {
    // prefetch x rows before (or instead of) phase-A work
#pragma unroll
    for (int r = 0; r < 8; ++r)
      xvA[r] = *(const float4*)&x[(size_t)(r0 + r) * 256 + lane * 4];
#pragma unroll
    for (int r = 0; r < 8; ++r)
      xvB[r] = *(const float4*)&x[(size_t)(r0 + 8 + r) * 256 + lane * 4];
  }

  if (bid < 16) {
    phaseA_kq(x, W, inb, kq, c4, sh, bid, t);
    signal_done(&cnt[0]);
#pragma unroll
    for (int r = 0; r < 8; ++r)
      xvA[r] = *(const float4*)&x[(size_t)(r0 + r) * 256 + lane * 4];
#pragma unroll
    for (int r = 0; r < 8; ++r)
      xvB[r] = *(const float4*)&x[(size_t)(r0 + 8 + r) * 256 + lane * 4];
  } else if (bid < 144) {
    phaseA_m2(W, Wout, M2, sh, bid - 16, t);
    signal_done(&cnt[1]);
  } else if (bid < 160) {
    phaseA_b2(Wout, inb, bout, bias2, sh, bid - 144, t);
    signal_done(&cnt[1]);
  }

  spin_until(&cnt[0], 16);  // kq/c4 ready
  phaseB_core(xvA, xvB, kq, c4, ypart, mpart, lpart, sh, bid, t);

  const int tk = take_ticket(&cnt[2], &shi);
  if (tk < NBLK - 64) return;
  spin_until(&cnt[2], NBLK);  // all B-partials visible
  phaseC(ypart, mpart, lpart, yv, sh, tk - (NBLK - 64), t);

  const int t2 = take_ticket(&cnt[3], &shi);
  if (t2 < 48) return;
  spin_until(&cnt[3], 64);    // all yv slices visible
  spin_until(&cnt[1], 144);   // M2 + bias2 visible (long done)
  phaseD(M2, yv, bias2, out, sh, t2 - 48, t);
}

// ---------------- Fallback chain (same phases, 4 launches) ----------------
__global__ void __launch_bounds__(512) fb_A(const float* __restrict__ x, const float* __restrict__ W,
                                            const float* __restrict__ inb, const float* __restrict__ Wout,
                                            const float* __restrict__ bout, float* __restrict__ ws) {
  __shared__ __align__(16) float sh[832];
  const int bid = blockIdx.x, t = threadIdx.x;
  if (bid < 16) phaseA_kq(x, W, inb, ws + WS_KQ, ws + WS_C4, sh, bid, t);
  else if (bid < 144) phaseA_m2(W, Wout, ws + WS_M2, sh, bid - 16, t);
  else if (bid < 160) phaseA_b2(Wout, inb, bout, ws + WS_B2, sh, bid - 144, t);
}
__global__ void __launch_bounds__(512) fb_B(const float* __restrict__ x, float* __restrict__ ws) {
  __shared__ __align__(16) float sh[8256];
  const int bid = blockIdx.x, t = threadIdx.x;
  const int lane = t & 63, w = t >> 6;
  const int r0 = bid * 128 + w * 16;
  float4 xvA[8], xvB[8];
#pragma unroll
  for (int r = 0; r < 8; ++r)
    xvA[r] = *(const float4*)&x[(size_t)(r0 + r) * 256 + lane * 4];
#pragma unroll
  for (int r = 0; r < 8; ++r)
    xvB[r] = *(const float4*)&x[(size_t)(r0 + 8 + r) * 256 + lane * 4];
  phaseB_core(xvA, xvB, ws + WS_KQ, ws + WS_C4, ws + WS_YP, ws + WS_MP, ws + WS_LP, sh, bid, t);
}
__global__ void __launch_bounds__(512) fb_C(float* __restrict__ ws) {
  __shared__ __align__(16) float sh[1280];
  phaseC(ws + WS_YP, ws + WS_MP, ws + WS_LP, ws + WS_YV, sh, blockIdx.x, threadIdx.x);
}
__global__ void __launch_bounds__(512) fb_D(float* __restrict__ out, float* __restrict__ ws) {
  __shared__ __align__(16) float sh[1536];
  phaseD(ws + WS_M2, ws + WS_YV, ws + WS_B2, out, sh, blockIdx.x, threadIdx.x);
}

extern "C" void kernel_launch(void* const* d_in, const int* in_sizes, int n_in,
                              void* d_out, int out_size, void* d_ws, size_t ws_size,
                              hipStream_t stream) {
  const float* x = (const float*)d_in[0];
  const float* W = (const float*)d_in[1];
  const float* inb = (const float*)d_in[2];
  const float* Wout = (const float*)d_in[3];
  const float* bout = (const float*)d_in[4];
  float* out = (float*)d_out;
  float* ws = (float*)d_ws;

  // zero sync counters every call (stream-ordered; graph-captures as memset node)
  hipMemsetAsync((void*)(ws + WS_CNT), 0, 16, stream);

  int dev = 0;
  (void)hipGetDevice(&dev);
  int coopAttr = 0, ncu = 0, occ = 0;
  bool coop = (hipDeviceGetAttribute(&coopAttr, hipDeviceAttributeCooperativeLaunch, dev) == hipSuccess) &&
              coopAttr != 0;
  coop = coop &&
         (hipDeviceGetAttribute(&ncu, hipDeviceAttributeMultiprocessorCount, dev) == hipSuccess);
  coop = coop &&
         (hipOccupancyMaxActiveBlocksPerMultiprocessor(&occ, mha_coop, 512, 0) == hipSuccess);
  coop = coop && (occ * ncu >= NBLK);

  if (coop) {
    void* args[] = {(void*)&x, (void*)&W, (void*)&inb, (void*)&Wout,
                    (void*)&bout, (void*)&out, (void*)&ws};
    if (hipLaunchCooperativeKernel((const void*)mha_coop, dim3(NBLK), dim3(512),
                                   args, 0, stream) == hipSuccess)
      return;
  }
  fb_A<<<160, 512, 0, stream>>>(x, W, inb, Wout, bout, ws);
  fb_B<<<NBLK, 512, 0, stream>>>(x, ws);
  fb_C<<<64, 512, 0, stream>>>(ws);
  fb_D<<<16, 512, 0, stream>>>(out, ws);
}